// Round 22
// baseline (189.714 us; speedup 1.0000x reference)
//
#include <hip/hip_runtime.h>
#include <hip/hip_bf16.h>
#include <cmath>
#include <stdint.h>

#define B_ 2
#define S_ 2048
#define D_ 2048
#define H_ 16
#define HKV_ 2
#define DH_ 128
#define G_ 8
#define DKV_ 256   // HKV*DH
#define NQKV_ 2560 // D_ + 2*DKV

typedef _Float16 f16;
typedef _Float16 f16x8 __attribute__((ext_vector_type(8)));
typedef _Float16 f16x4 __attribute__((ext_vector_type(4)));
typedef float f32x4 __attribute__((ext_vector_type(4)));

__device__ __forceinline__ void gload_lds16(const void* g, void* lds) {
  __builtin_amdgcn_global_load_lds((const __attribute__((address_space(1))) void*)g,
                                   (__attribute__((address_space(3))) void*)lds,
                                   16, 0, 0);
}

// raw v_exp_f32 (2^x): skips the compiler's denormal-range fixup.
__device__ __forceinline__ float fexp2(float x) {
  float r;
  asm("v_exp_f32 %0, %1" : "=v"(r) : "v"(x));
  return r;
}

// One fused prep pass: all weight/x casts (f32->f16, float4-vectorized) plus
// the bias concat (f32 copy).  Segment bounds are compile-time constants.
__global__ void prep_kernel(const float* __restrict__ x,  const float* __restrict__ Wq,
                            const float* __restrict__ Wk, const float* __restrict__ Wv,
                            const float* __restrict__ Wo, const float* __restrict__ bq,
                            const float* __restrict__ bk, const float* __restrict__ bv,
                            f16* __restrict__ xh, f16* __restrict__ wqkv,
                            f16* __restrict__ woh, float* __restrict__ bqkv) {
  constexpr int N0 = 2097152;            // x        (float4 units)
  constexpr int N1 = N0 + 1048576;       // Wq
  constexpr int N2 = N1 + 131072;        // Wk
  constexpr int N3 = N2 + 131072;        // Wv
  constexpr int N4 = N3 + 1048576;       // Wo
  constexpr int N5 = N4 + 512;           // bq
  constexpr int N6 = N5 + 64;            // bk
  constexpr int N7 = N6 + 64;            // bv
  int i = blockIdx.x * blockDim.x + threadIdx.x;
  const int stride = gridDim.x * blockDim.x;
  for (; i < N7; i += stride) {
    if (i < N4) {
      const float* s; f16x4* d; int j;
      if (i < N0)      { s = x;  d = (f16x4*)xh;             j = i; }
      else if (i < N1) { s = Wq; d = (f16x4*)wqkv;           j = i - N0; }
      else if (i < N2) { s = Wk; d = (f16x4*)wqkv + 1048576; j = i - N1; }
      else if (i < N3) { s = Wv; d = (f16x4*)wqkv + 1179648; j = i - N2; }
      else             { s = Wo; d = (f16x4*)woh;            j = i - N3; }
      float4 v = reinterpret_cast<const float4*>(s)[j];
      f16x4 o = { (f16)v.x, (f16)v.y, (f16)v.z, (f16)v.w };
      d[j] = o;
    } else {
      const float* s; int off, j;
      if (i < N5)      { s = bq; off = 0;   j = i - N4; }
      else if (i < N6) { s = bk; off = 512; j = i - N5; }
      else             { s = bv; off = 576; j = i - N6; }
      reinterpret_cast<float4*>(bqkv)[off + j] = reinterpret_cast<const float4*>(s)[j];
    }
  }
}

// C[m][n] = sum_k A[m][k]*Bm[n][k] + bias[n].  1-D grid (nwg % 8 == 0), XCD-swizzled.
// Single-buffered 32KB LDS (m97 2-barrier structure); swizzled tiles.  (r19-exact)
template<int EPI>
__global__ __launch_bounds__(256)
void gemm_core(const f16* __restrict__ A, const f16* __restrict__ Bm,
               const float* __restrict__ bias,
               f16* __restrict__ oQ, f16* __restrict__ oK, f16* __restrict__ oV,
               float* __restrict__ oF,
               int M, int N, int K, int nbx) {
  __shared__ __align__(16) f16 sA[128 * 64];
  __shared__ __align__(16) f16 sB[128 * 64];
  const int tid  = threadIdx.x;
  const int lane = tid & 63;
  const int w    = tid >> 6;
  const int wr   = w >> 1, wc = w & 1;
  const int r16  = lane & 15, grp = lane >> 4;
  const int nwg  = gridDim.x;
  const int cpx  = nwg >> 3;
  const int lg   = (blockIdx.x & 7) * cpx + (blockIdx.x >> 3);  // bijective XCD swizzle
  const int bm   = (lg / nbx) * 128;
  const int bn   = (lg % nbx) * 128;

  f32x4 acc[4][4] = {};

  auto stage = [&](int k0) {   // 8 gload_lds per thread; swizzled source
#pragma unroll
    for (int j = 0; j < 4; ++j) {
      int seg = j * 4 + w;                 // 8-row segment
      int rr  = seg * 8 + (lane >> 3);     // row in tile
      int cs  = lane & 7;                  // stored chunk index (linear in LDS)
      int csr = (cs ^ (rr & 7)) * 8;       // source column (pre-swizzled)
      gload_lds16(A  + (size_t)(bm + rr) * K + k0 + csr, &sA[seg * 512]);
      gload_lds16(Bm + (size_t)(bn + rr) * K + k0 + csr, &sB[seg * 512]);
    }
  };

  const int nk = K >> 6;
  for (int t = 0; t < nk; ++t) {
    stage(t << 6);
    asm volatile("s_waitcnt vmcnt(0)" ::: "memory");  // tile landed
    __builtin_amdgcn_s_barrier();

#pragma unroll
    for (int kk = 0; kk < 64; kk += 32) {
      f16x8 af[4], bf[4];
      const int cb = (kk >> 3) + grp;        // logical chunk of this fragment
      const int cx = (cb ^ (r16 & 7)) << 3;  // swizzled f16 offset within row
#pragma unroll
      for (int m = 0; m < 4; ++m)
        af[m] = *reinterpret_cast<const f16x8*>(&sA[(wr * 64 + m * 16 + r16) * 64 + cx]);
#pragma unroll
      for (int n = 0; n < 4; ++n)
        bf[n] = *reinterpret_cast<const f16x8*>(&sB[(wc * 64 + n * 16 + r16) * 64 + cx]);
#pragma unroll
      for (int m = 0; m < 4; ++m)
#pragma unroll
        for (int n = 0; n < 4; ++n)
          acc[m][n] = __builtin_amdgcn_mfma_f32_16x16x32_f16(af[m], bf[n], acc[m][n], 0, 0, 0);
    }

    __builtin_amdgcn_s_barrier();   // all waves done reading; safe to restage
  }

#pragma unroll
  for (int n = 0; n < 4; ++n) {
    int col = bn + wc * 64 + n * 16 + r16;
    float bv = bias ? bias[col] : 0.f;
#pragma unroll
    for (int m = 0; m < 4; ++m) {
      int row0 = bm + wr * 64 + m * 16 + grp * 4;   // 4-aligned
      if constexpr (EPI == 0) {
#pragma unroll
        for (int j = 0; j < 4; ++j)
          oF[(size_t)(row0 + j) * N + col] = acc[m][n][j] + bv;
      } else {
        if (bn < 2048) {
#pragma unroll
          for (int j = 0; j < 4; ++j)
            oQ[(size_t)(row0 + j) * 2048 + col] = (f16)(acc[m][n][j] + bv);
        } else if (bn < 2304) {
#pragma unroll
          for (int j = 0; j < 4; ++j)
            oK[(size_t)(row0 + j) * 256 + (col - 2048)] = (f16)(acc[m][n][j] + bv);
        } else {
          f16x4 st;
#pragma unroll
          for (int j = 0; j < 4; ++j) st[j] = (f16)(acc[m][n][j] + bv);
          *reinterpret_cast<f16x4*>(&oV[(size_t)(row0 >> 2) * 1024 + (col - 2304) * 4]) = st;
        }
      }
    }
  }
}

// Flash attention, causal, GQA.  512 blocks, ONE task each; 4 waves/block;
// EACH WAVE HANDLES 2 HEADS (w, w+4 of the kv-group): K/V LDS fragments are
// read once per wave and MFMA'd against two Q operands (halves LDS-pipe load,
// which r21 counters show is ~80% of the block-tile critical path).
// qt map balanced for both {c,c+256} and {2c,2c+1} CU-pairings:
//   v = ((bid>>3)&31)*2 + (bid&1);  qt = (bid&256) ? 127-v : v.
// KVBLK=64, 2-buffer LDS, depth-1 prefetch, branch-free main loop,
// merged 64-wide online softmax per head (r21 body, duplicated state).
__global__ __launch_bounds__(256)
void attn_kernel(const f16* __restrict__ Q, const f16* __restrict__ K,
                 const f16* __restrict__ V4, f16* __restrict__ O) {
  __shared__ __align__(16) f16 sK[2][8192];   // [buf][64 rows x 128], XOR-swizzled 16B chunks
  __shared__ __align__(16) f16 sV[2][8192];   // [buf][16 grp x 512],  XOR-swizzled 16B chunks

  const int tid  = threadIdx.x;
  const int lane = tid & 63;
  const int w    = tid >> 6;
  const int qi   = lane & 15, grp = lane >> 4;
  const int bid  = blockIdx.x;
  const int b    = (bid >> 1) & 1;
  const int kvh  = (bid >> 2) & 1;
  const int v_   = ((bid >> 3) & 31) * 2 + (bid & 1);
  const int qt   = (bid & 256) ? (127 - v_) : v_;
  const int hqA  = kvh * 8 + w;
  const int hqB  = kvh * 8 + 4 + w;
  const f16 SCL2 = (f16)(0.08838834764831845f * 1.44269504088896f);  // 1/sqrt(128)*log2(e)

  const f16* Kb = K  + (size_t)b * S_ * DKV_ + kvh * DH_;
  const f16* Vb = V4 + (size_t)b * S_ * DKV_ + kvh * 512;

  auto stage = [&](int t64, int buf) {   // exactly 8 vm loads per thread (64 kv rows)
#pragma unroll
    for (int p4 = 0; p4 < 4; ++p4) {
      int ci = p4 * 256 + tid;
      int r = ci >> 4, cs = ci & 15;
      gload_lds16(Kb + (size_t)(t64 * 64 + r) * DKV_ + ((cs ^ (r & 7)) * 8),
                  (char*)&sK[buf][0] + p4 * 4096 + w * 1024);
      int g = ci >> 6, cc = ci & 63;
      gload_lds16(Vb + (size_t)(t64 * 16 + g) * 1024 + ((cc ^ g) * 8),
                  (char*)&sV[buf][0] + p4 * 4096 + w * 1024);
    }
  };

  // PV address decomposition (lane-fixed)
  const int q2    = qi >> 1;
  const int voff0 = ((q2 ^ grp) << 3) + (qi & 1) * 4;
  const int voff1 = ((q2 ^ (grp + 4)) << 3) + (qi & 1) * 4;

  const int nt    = (qt >> 2) + 1;          // 64-kv tiles
  const int q_pos = qt * 16 + qi;

  const size_t qrow = ((size_t)(b * S_ + qt * 16 + qi)) * D_;
  f16x8 qfA[4], qfB[4];
#pragma unroll
  for (int kd = 0; kd < 4; ++kd) {
    qfA[kd] = *reinterpret_cast<const f16x8*>(Q + qrow + hqA * DH_ + kd * 32 + grp * 8);
    qfB[kd] = *reinterpret_cast<const f16x8*>(Q + qrow + hqB * DH_ + kd * 32 + grp * 8);
#pragma unroll
    for (int e = 0; e < 8; ++e) { qfA[kd][e] *= SCL2; qfB[kd][e] *= SCL2; }
  }

  float mA = -INFINITY, lsA = 0.f;
  float mB = -INFINITY, lsB = 0.f;
  f32x4 accA[8] = {}, accB[8] = {};

  // one full 64-kv tile for BOTH heads: K/V frags read once, used twice.
  auto tile_step = [&](const f16* sKb, const f16* sVb, int kv0, bool MASK) {
    f32x4 sA0 = {}, sA1 = {}, sA2 = {}, sA3 = {};
    f32x4 sB0 = {}, sB1 = {}, sB2 = {}, sB3 = {};
#pragma unroll
    for (int kd = 0; kd < 4; ++kd) {
      const int cx = ((kd * 4 + grp) ^ (qi & 7)) << 3;
      f16x8 k0 = *reinterpret_cast<const f16x8*>(sKb + qi * 128 + cx);
      f16x8 k1 = *reinterpret_cast<const f16x8*>(sKb + (16 + qi) * 128 + cx);
      f16x8 k2 = *reinterpret_cast<const f16x8*>(sKb + (32 + qi) * 128 + cx);
      f16x8 k3 = *reinterpret_cast<const f16x8*>(sKb + (48 + qi) * 128 + cx);
      sA0 = __builtin_amdgcn_mfma_f32_16x16x32_f16(k0, qfA[kd], sA0, 0, 0, 0);
      sB0 = __builtin_amdgcn_mfma_f32_16x16x32_f16(k0, qfB[kd], sB0, 0, 0, 0);
      sA1 = __builtin_amdgcn_mfma_f32_16x16x32_f16(k1, qfA[kd], sA1, 0, 0, 0);
      sB1 = __builtin_amdgcn_mfma_f32_16x16x32_f16(k1, qfB[kd], sB1, 0, 0, 0);
      sA2 = __builtin_amdgcn_mfma_f32_16x16x32_f16(k2, qfA[kd], sA2, 0, 0, 0);
      sB2 = __builtin_amdgcn_mfma_f32_16x16x32_f16(k2, qfB[kd], sB2, 0, 0, 0);
      sA3 = __builtin_amdgcn_mfma_f32_16x16x32_f16(k3, qfA[kd], sA3, 0, 0, 0);
      sB3 = __builtin_amdgcn_mfma_f32_16x16x32_f16(k3, qfB[kd], sB3, 0, 0, 0);
    }
    float pA[16], pB[16];
#pragma unroll
    for (int jj = 0; jj < 4; ++jj) {
      pA[jj] = sA0[jj]; pA[4 + jj] = sA1[jj]; pA[8 + jj] = sA2[jj]; pA[12 + jj] = sA3[jj];
      pB[jj] = sB0[jj]; pB[4 + jj] = sB1[jj]; pB[8 + jj] = sB2[jj]; pB[12 + jj] = sB3[jj];
    }
    if (MASK) {
#pragma unroll
      for (int qd = 0; qd < 4; ++qd)
#pragma unroll
        for (int jj = 0; jj < 4; ++jj) {
          int kvp = kv0 + qd * 16 + grp * 4 + jj;
          bool msk = kvp > q_pos;
          pA[qd * 4 + jj] = msk ? -INFINITY : pA[qd * 4 + jj];
          pB[qd * 4 + jj] = msk ? -INFINITY : pB[qd * 4 + jj];
        }
    }
    // depth-4 pairwise max trees
    float tmA, tmB;
    {
      float a0 = fmaxf(pA[0], pA[8]),  a1 = fmaxf(pA[1], pA[9]);
      float a2 = fmaxf(pA[2], pA[10]), a3 = fmaxf(pA[3], pA[11]);
      float a4 = fmaxf(pA[4], pA[12]), a5 = fmaxf(pA[5], pA[13]);
      float a6 = fmaxf(pA[6], pA[14]), a7 = fmaxf(pA[7], pA[15]);
      a0 = fmaxf(a0, a4); a1 = fmaxf(a1, a5); a2 = fmaxf(a2, a6); a3 = fmaxf(a3, a7);
      tmA = fmaxf(fmaxf(a0, a2), fmaxf(a1, a3));
      float b0 = fmaxf(pB[0], pB[8]),  b1 = fmaxf(pB[1], pB[9]);
      float b2 = fmaxf(pB[2], pB[10]), b3 = fmaxf(pB[3], pB[11]);
      float b4 = fmaxf(pB[4], pB[12]), b5 = fmaxf(pB[5], pB[13]);
      float b6 = fmaxf(pB[6], pB[14]), b7 = fmaxf(pB[7], pB[15]);
      b0 = fmaxf(b0, b4); b1 = fmaxf(b1, b5); b2 = fmaxf(b2, b6); b3 = fmaxf(b3, b7);
      tmB = fmaxf(fmaxf(b0, b2), fmaxf(b1, b3));
    }
    if (!__all((tmA <= mA + 8.f) && (tmB <= mB + 8.f))) {   // rare rescale path
      float rA = tmA, rB = tmB;
      rA = fmaxf(rA, __shfl_xor(rA, 16)); rA = fmaxf(rA, __shfl_xor(rA, 32));
      rB = fmaxf(rB, __shfl_xor(rB, 16)); rB = fmaxf(rB, __shfl_xor(rB, 32));
      float mnA = fmaxf(mA, rA), mnB = fmaxf(mB, rB);
      float scA = fexp2(mA - mnA), scB = fexp2(mB - mnB);
      mA = mnA; mB = mnB;
      lsA *= scA; lsB *= scB;
#pragma unroll
      for (int dt = 0; dt < 8; ++dt)
#pragma unroll
        for (int jj = 0; jj < 4; ++jj) { accA[dt][jj] *= scA; accB[dt][jj] *= scB; }
    }
    float psA = 0.f, psB = 0.f;
#pragma unroll
    for (int i = 0; i < 16; ++i) {
      pA[i] = fexp2(pA[i] - mA); psA += pA[i];
      pB[i] = fexp2(pB[i] - mB); psB += pB[i];
    }
    lsA += psA; lsB += psB;

    f16x4 pfA0 = { (f16)pA[0],  (f16)pA[1],  (f16)pA[2],  (f16)pA[3]  };
    f16x4 pfA1 = { (f16)pA[4],  (f16)pA[5],  (f16)pA[6],  (f16)pA[7]  };
    f16x4 pfA2 = { (f16)pA[8],  (f16)pA[9],  (f16)pA[10], (f16)pA[11] };
    f16x4 pfA3 = { (f16)pA[12], (f16)pA[13], (f16)pA[14], (f16)pA[15] };
    f16x4 pfB0 = { (f16)pB[0],  (f16)pB[1],  (f16)pB[2],  (f16)pB[3]  };
    f16x4 pfB1 = { (f16)pB[4],  (f16)pB[5],  (f16)pB[6],  (f16)pB[7]  };
    f16x4 pfB2 = { (f16)pB[8],  (f16)pB[9],  (f16)pB[10], (f16)pB[11] };
    f16x4 pfB3 = { (f16)pB[12], (f16)pB[13], (f16)pB[14], (f16)pB[15] };
    const f16* vb0 = sVb + grp * 512 + voff0;
    const f16* vb1 = sVb + (grp + 4) * 512 + voff1;
    const f16* vb2 = sVb + (8 + grp) * 512 + voff0;
    const f16* vb3 = sVb + (12 + grp) * 512 + voff1;
#pragma unroll
    for (int dtp = 0; dtp < 8; ++dtp) {
      const int dt1 = dtp ^ 1;
      f16x4 v0 = *reinterpret_cast<const f16x4*>(vb0 + dtp * 64);
      f16x4 v1 = *reinterpret_cast<const f16x4*>(vb1 + dtp * 64);
      f16x4 v2 = *reinterpret_cast<const f16x4*>(vb2 + dtp * 64);
      f16x4 v3 = *reinterpret_cast<const f16x4*>(vb3 + dtp * 64);
      accA[dtp] = __builtin_amdgcn_mfma_f32_16x16x16f16(v0, pfA0, accA[dtp], 0, 0, 0);
      accB[dtp] = __builtin_amdgcn_mfma_f32_16x16x16f16(v0, pfB0, accB[dtp], 0, 0, 0);
      accA[dtp] = __builtin_amdgcn_mfma_f32_16x16x16f16(v1, pfA1, accA[dtp], 0, 0, 0);
      accB[dtp] = __builtin_amdgcn_mfma_f32_16x16x16f16(v1, pfB1, accB[dtp], 0, 0, 0);
      accA[dt1] = __builtin_amdgcn_mfma_f32_16x16x16f16(v2, pfA2, accA[dt1], 0, 0, 0);
      accB[dt1] = __builtin_amdgcn_mfma_f32_16x16x16f16(v2, pfB2, accB[dt1], 0, 0, 0);
      accA[dt1] = __builtin_amdgcn_mfma_f32_16x16x16f16(v3, pfA3, accA[dt1], 0, 0, 0);
      accB[dt1] = __builtin_amdgcn_mfma_f32_16x16x16f16(v3, pfB3, accB[dt1], 0, 0, 0);
    }
  };

  stage(0, 0);
  asm volatile("s_waitcnt vmcnt(0)" ::: "memory");
  __builtin_amdgcn_s_barrier();

  // ---- main loop: branch-free, unmasked, always prefetch ----
  for (int t = 0; t < nt - 1; ++t) {
    const int buf = t & 1;
    stage(t + 1, buf ^ 1);
    tile_step(&sK[buf][0], &sV[buf][0], t * 64, false);
    asm volatile("s_waitcnt vmcnt(0)" ::: "memory");
    __builtin_amdgcn_s_barrier();
  }

  // ---- peeled last tile: causal mask (fully-masked rows exp to 0) ----
  {
    const int t = nt - 1, buf = t & 1;
    tile_step(&sK[buf][0], &sV[buf][0], t * 64, true);
  }

  lsA += __shfl_xor(lsA, 16); lsA += __shfl_xor(lsA, 32);
  lsB += __shfl_xor(lsB, 16); lsB += __shfl_xor(lsB, 32);
  float ilA = 1.f / lsA, ilB = 1.f / lsB;
  const size_t obA = qrow + hqA * DH_;
  const size_t obB = qrow + hqB * DH_;
#pragma unroll
  for (int dt = 0; dt < 8; ++dt) {
    f16x4 stA, stB;
#pragma unroll
    for (int jj = 0; jj < 4; ++jj) {
      stA[jj] = (f16)(accA[dt][jj] * ilA);
      stB[jj] = (f16)(accB[dt][jj] * ilB);
    }
    *reinterpret_cast<f16x4*>(&O[obA + dt * 16 + grp * 4]) = stA;
    *reinterpret_cast<f16x4*>(&O[obB + dt * 16 + grp * 4]) = stB;
  }
}

extern "C" void kernel_launch(void* const* d_in, const int* in_sizes, int n_in,
                              void* d_out, int out_size, void* d_ws, size_t ws_size,
                              hipStream_t stream) {
  const float* x  = (const float*)d_in[0];
  const float* Wq = (const float*)d_in[1];
  const float* bq = (const float*)d_in[2];
  const float* Wk = (const float*)d_in[3];
  const float* bk = (const float*)d_in[4];
  const float* Wv = (const float*)d_in[5];
  const float* bv = (const float*)d_in[6];
  const float* Wo = (const float*)d_in[7];
  const float* bo = (const float*)d_in[8];
  float* out = (float*)d_out;

  char* ws = (char*)d_ws;
  size_t off = 0;
  auto alloc = [&](size_t bytes) {
    char* p = ws + off;
    off += (bytes + 255) & ~(size_t)255;
    return p;
  };
  f16*   xh    = (f16*)alloc((size_t)B_ * S_ * D_ * 2);
  f16*   wqkv  = (f16*)alloc((size_t)NQKV_ * D_ * 2);
  f16*   woh   = (f16*)alloc((size_t)D_ * D_ * 2);
  f16*   qh    = (f16*)alloc((size_t)B_ * S_ * D_ * 2);
  f16*   kh    = (f16*)alloc((size_t)B_ * S_ * DKV_ * 2);
  f16*   v4h   = (f16*)alloc((size_t)B_ * S_ * DKV_ * 2);
  f16*   ah    = (f16*)alloc((size_t)B_ * S_ * D_ * 2);
  float* bqkv  = (float*)alloc((size_t)NQKV_ * 4);

  prep_kernel<<<dim3(2048), dim3(256), 0, stream>>>(
      x, Wq, Wk, Wv, Wo, bq, bk, bv, xh, wqkv, woh, bqkv);

  const int M = B_ * S_;
  gemm_core<1><<<dim3((M / 128) * (NQKV_ / 128)), 256, 0, stream>>>(
      xh, wqkv, bqkv, qh, kh, v4h, nullptr, M, NQKV_, D_, NQKV_ / 128);

  attn_kernel<<<dim3(512), 256, 0, stream>>>(qh, kh, v4h, ah);

  gemm_core<0><<<dim3((M / 128) * (D_ / 128)), 256, 0, stream>>>(
      ah, woh, bo, nullptr, nullptr, nullptr, out, M, D_, D_, D_ / 128);
}

// Round 23
// 184.482 us; speedup vs baseline: 1.0284x; 1.0284x over previous
//
#include <hip/hip_runtime.h>
#include <hip/hip_bf16.h>
#include <cmath>
#include <stdint.h>

#define B_ 2
#define S_ 2048
#define D_ 2048
#define H_ 16
#define HKV_ 2
#define DH_ 128
#define G_ 8
#define DKV_ 256   // HKV*DH
#define NQKV_ 2560 // D_ + 2*DKV

typedef _Float16 f16;
typedef _Float16 f16x8 __attribute__((ext_vector_type(8)));
typedef _Float16 f16x4 __attribute__((ext_vector_type(4)));
typedef float f32x4 __attribute__((ext_vector_type(4)));

__device__ __forceinline__ void gload_lds16(const void* g, void* lds) {
  __builtin_amdgcn_global_load_lds((const __attribute__((address_space(1))) void*)g,
                                   (__attribute__((address_space(3))) void*)lds,
                                   16, 0, 0);
}

// raw v_exp_f32 (2^x): skips the compiler's denormal-range fixup.
__device__ __forceinline__ float fexp2(float x) {
  float r;
  asm("v_exp_f32 %0, %1" : "=v"(r) : "v"(x));
  return r;
}

// One fused prep pass: all weight/x casts (f32->f16, float4-vectorized) plus
// the bias concat (f32 copy).  Segment bounds are compile-time constants.
__global__ void prep_kernel(const float* __restrict__ x,  const float* __restrict__ Wq,
                            const float* __restrict__ Wk, const float* __restrict__ Wv,
                            const float* __restrict__ Wo, const float* __restrict__ bq,
                            const float* __restrict__ bk, const float* __restrict__ bv,
                            f16* __restrict__ xh, f16* __restrict__ wqkv,
                            f16* __restrict__ woh, float* __restrict__ bqkv) {
  constexpr int N0 = 2097152;            // x        (float4 units)
  constexpr int N1 = N0 + 1048576;       // Wq
  constexpr int N2 = N1 + 131072;        // Wk
  constexpr int N3 = N2 + 131072;        // Wv
  constexpr int N4 = N3 + 1048576;       // Wo
  constexpr int N5 = N4 + 512;           // bq
  constexpr int N6 = N5 + 64;            // bk
  constexpr int N7 = N6 + 64;            // bv
  int i = blockIdx.x * blockDim.x + threadIdx.x;
  const int stride = gridDim.x * blockDim.x;
  for (; i < N7; i += stride) {
    if (i < N4) {
      const float* s; f16x4* d; int j;
      if (i < N0)      { s = x;  d = (f16x4*)xh;             j = i; }
      else if (i < N1) { s = Wq; d = (f16x4*)wqkv;           j = i - N0; }
      else if (i < N2) { s = Wk; d = (f16x4*)wqkv + 1048576; j = i - N1; }
      else if (i < N3) { s = Wv; d = (f16x4*)wqkv + 1179648; j = i - N2; }
      else             { s = Wo; d = (f16x4*)woh;            j = i - N3; }
      float4 v = reinterpret_cast<const float4*>(s)[j];
      f16x4 o = { (f16)v.x, (f16)v.y, (f16)v.z, (f16)v.w };
      d[j] = o;
    } else {
      const float* s; int off, j;
      if (i < N5)      { s = bq; off = 0;   j = i - N4; }
      else if (i < N6) { s = bk; off = 512; j = i - N5; }
      else             { s = bv; off = 576; j = i - N6; }
      reinterpret_cast<float4*>(bqkv)[off + j] = reinterpret_cast<const float4*>(s)[j];
    }
  }
}

// C[m][n] = sum_k A[m][k]*Bm[n][k] + bias[n].  1-D grid (nwg % 8 == 0), XCD-swizzled.
// Single-buffered 32KB LDS (m97 2-barrier structure); swizzled tiles.
template<int EPI>
__global__ __launch_bounds__(256)
void gemm_core(const f16* __restrict__ A, const f16* __restrict__ Bm,
               const float* __restrict__ bias,
               f16* __restrict__ oQ, f16* __restrict__ oK, f16* __restrict__ oV,
               float* __restrict__ oF,
               int M, int N, int K, int nbx) {
  __shared__ __align__(16) f16 sA[128 * 64];
  __shared__ __align__(16) f16 sB[128 * 64];
  const int tid  = threadIdx.x;
  const int lane = tid & 63;
  const int w    = tid >> 6;
  const int wr   = w >> 1, wc = w & 1;
  const int r16  = lane & 15, grp = lane >> 4;
  const int nwg  = gridDim.x;
  const int cpx  = nwg >> 3;
  const int lg   = (blockIdx.x & 7) * cpx + (blockIdx.x >> 3);  // bijective XCD swizzle
  const int bm   = (lg / nbx) * 128;
  const int bn   = (lg % nbx) * 128;

  f32x4 acc[4][4] = {};

  auto stage = [&](int k0) {   // 8 gload_lds per thread; swizzled source
#pragma unroll
    for (int j = 0; j < 4; ++j) {
      int seg = j * 4 + w;                 // 8-row segment
      int rr  = seg * 8 + (lane >> 3);     // row in tile
      int cs  = lane & 7;                  // stored chunk index (linear in LDS)
      int csr = (cs ^ (rr & 7)) * 8;       // source column (pre-swizzled)
      gload_lds16(A  + (size_t)(bm + rr) * K + k0 + csr, &sA[seg * 512]);
      gload_lds16(Bm + (size_t)(bn + rr) * K + k0 + csr, &sB[seg * 512]);
    }
  };

  const int nk = K >> 6;
  for (int t = 0; t < nk; ++t) {
    stage(t << 6);
    asm volatile("s_waitcnt vmcnt(0)" ::: "memory");  // tile landed
    __builtin_amdgcn_s_barrier();

#pragma unroll
    for (int kk = 0; kk < 64; kk += 32) {
      f16x8 af[4], bf[4];
      const int cb = (kk >> 3) + grp;        // logical chunk of this fragment
      const int cx = (cb ^ (r16 & 7)) << 3;  // swizzled f16 offset within row
#pragma unroll
      for (int m = 0; m < 4; ++m)
        af[m] = *reinterpret_cast<const f16x8*>(&sA[(wr * 64 + m * 16 + r16) * 64 + cx]);
#pragma unroll
      for (int n = 0; n < 4; ++n)
        bf[n] = *reinterpret_cast<const f16x8*>(&sB[(wc * 64 + n * 16 + r16) * 64 + cx]);
#pragma unroll
      for (int m = 0; m < 4; ++m)
#pragma unroll
        for (int n = 0; n < 4; ++n)
          acc[m][n] = __builtin_amdgcn_mfma_f32_16x16x32_f16(af[m], bf[n], acc[m][n], 0, 0, 0);
    }

    __builtin_amdgcn_s_barrier();   // all waves done reading; safe to restage
  }

#pragma unroll
  for (int n = 0; n < 4; ++n) {
    int col = bn + wc * 64 + n * 16 + r16;
    float bv = bias ? bias[col] : 0.f;
#pragma unroll
    for (int m = 0; m < 4; ++m) {
      int row0 = bm + wr * 64 + m * 16 + grp * 4;   // 4-aligned
      if constexpr (EPI == 0) {
#pragma unroll
        for (int j = 0; j < 4; ++j)
          oF[(size_t)(row0 + j) * N + col] = acc[m][n][j] + bv;
      } else {
        if (bn < 2048) {
#pragma unroll
          for (int j = 0; j < 4; ++j)
            oQ[(size_t)(row0 + j) * 2048 + col] = (f16)(acc[m][n][j] + bv);
        } else if (bn < 2304) {
#pragma unroll
          for (int j = 0; j < 4; ++j)
            oK[(size_t)(row0 + j) * 256 + (col - 2048)] = (f16)(acc[m][n][j] + bv);
        } else {
          f16x4 st;
#pragma unroll
          for (int j = 0; j < 4; ++j) st[j] = (f16)(acc[m][n][j] + bv);
          *reinterpret_cast<f16x4*>(&oV[(size_t)(row0 >> 2) * 1024 + (col - 2304) * 4]) = st;
        }
      }
    }
  }
}

// Flash attention, causal, GQA.  512 blocks, TWO tasks each (qt = 127-j then j).
// Block = 4 waves = 4 q-heads sharing one kv-head's K/V LDS tiles.
// KVBLK=64, 2-buffer LDS, depth-1 prefetch, branch-free main loop (r20),
// ONE merged 64-wide online softmax per tile (r21): single vote/rescale;
// 16 QK-MFMAs and 32 PV-MFMAs in unbroken runs; explicit depth-4 max tree.
__global__ __launch_bounds__(256)
void attn_kernel(const f16* __restrict__ Q, const f16* __restrict__ K,
                 const f16* __restrict__ V4, f16* __restrict__ O) {
  __shared__ __align__(16) f16 sK[2][8192];   // [buf][64 rows x 128], XOR-swizzled 16B chunks
  __shared__ __align__(16) f16 sV[2][8192];   // [buf][16 grp x 512],  XOR-swizzled 16B chunks

  const int tid  = threadIdx.x;
  const int lane = tid & 63;
  const int w    = tid >> 6;
  const int qi   = lane & 15, grp = lane >> 4;
  const int bid  = blockIdx.x;
  const int hh   = bid & 1;
  const int kvh  = (bid >> 1) & 1;
  const int b    = (bid >> 2) & 1;
  const int j    = bid >> 3;           // 0..63
  const int hq   = kvh * 8 + hh * 4 + w;
  const f16 SCL2 = (f16)(0.08838834764831845f * 1.44269504088896f);  // 1/sqrt(128)*log2(e)

  const f16* Kb = K  + (size_t)b * S_ * DKV_ + kvh * DH_;
  const f16* Vb = V4 + (size_t)b * S_ * DKV_ + kvh * 512;

  auto stage = [&](int t64, int buf) {   // exactly 8 vm loads per thread (64 kv rows)
#pragma unroll
    for (int p4 = 0; p4 < 4; ++p4) {
      int ci = p4 * 256 + tid;
      int r = ci >> 4, cs = ci & 15;
      gload_lds16(Kb + (size_t)(t64 * 64 + r) * DKV_ + ((cs ^ (r & 7)) * 8),
                  (char*)&sK[buf][0] + p4 * 4096 + w * 1024);
      int g = ci >> 6, cc = ci & 63;
      gload_lds16(Vb + (size_t)(t64 * 16 + g) * 1024 + ((cc ^ g) * 8),
                  (char*)&sV[buf][0] + p4 * 4096 + w * 1024);
    }
  };

  // PV address decomposition (task-invariant parts)
  const int q2    = qi >> 1;
  const int voff0 = ((q2 ^ grp) << 3) + (qi & 1) * 4;
  const int voff1 = ((q2 ^ (grp + 4)) << 3) + (qi & 1) * 4;

  for (int task = 0; task < 2; ++task) {
    const int qt    = task ? j : (127 - j);   // long task first
    const int nt    = (qt >> 2) + 1;          // 64-kv tiles
    const int q_pos = qt * 16 + qi;

    const size_t qbase = ((size_t)(b * S_ + qt * 16 + qi)) * D_ + hq * DH_;
    f16x8 qf[4];
#pragma unroll
    for (int kd = 0; kd < 4; ++kd) {
      qf[kd] = *reinterpret_cast<const f16x8*>(Q + qbase + kd * 32 + grp * 8);
#pragma unroll
      for (int e = 0; e < 8; ++e) qf[kd][e] *= SCL2;
    }

    float m = -INFINITY, lsum = 0.f;
    f32x4 accO[8] = {};

    // one full 64-kv tile: 16 QK-MFMAs, ONE 64-wide online softmax, 32 PV-MFMAs.
    auto tile_step = [&](const f16* sKb, const f16* sVb, int kv0, bool MASK) {
      f32x4 s0 = {}, s1 = {}, s2 = {}, s3 = {};
#pragma unroll
      for (int kd = 0; kd < 4; ++kd) {
        const int cx = ((kd * 4 + grp) ^ (qi & 7)) << 3;
        f16x8 k0 = *reinterpret_cast<const f16x8*>(sKb + qi * 128 + cx);
        f16x8 k1 = *reinterpret_cast<const f16x8*>(sKb + (16 + qi) * 128 + cx);
        f16x8 k2 = *reinterpret_cast<const f16x8*>(sKb + (32 + qi) * 128 + cx);
        f16x8 k3 = *reinterpret_cast<const f16x8*>(sKb + (48 + qi) * 128 + cx);
        s0 = __builtin_amdgcn_mfma_f32_16x16x32_f16(k0, qf[kd], s0, 0, 0, 0);
        s1 = __builtin_amdgcn_mfma_f32_16x16x32_f16(k1, qf[kd], s1, 0, 0, 0);
        s2 = __builtin_amdgcn_mfma_f32_16x16x32_f16(k2, qf[kd], s2, 0, 0, 0);
        s3 = __builtin_amdgcn_mfma_f32_16x16x32_f16(k3, qf[kd], s3, 0, 0, 0);
      }
      float p[16];
#pragma unroll
      for (int jj = 0; jj < 4; ++jj) {
        p[jj] = s0[jj]; p[4 + jj] = s1[jj]; p[8 + jj] = s2[jj]; p[12 + jj] = s3[jj];
      }
      if (MASK) {
#pragma unroll
        for (int qd = 0; qd < 4; ++qd)
#pragma unroll
          for (int jj = 0; jj < 4; ++jj) {
            int kvp = kv0 + qd * 16 + grp * 4 + jj;
            p[qd * 4 + jj] = (kvp > q_pos) ? -INFINITY : p[qd * 4 + jj];
          }
      }
      // depth-4 pairwise max tree over 16
      float a0 = fmaxf(p[0], p[8]),  a1 = fmaxf(p[1], p[9]);
      float a2 = fmaxf(p[2], p[10]), a3 = fmaxf(p[3], p[11]);
      float a4 = fmaxf(p[4], p[12]), a5 = fmaxf(p[5], p[13]);
      float a6 = fmaxf(p[6], p[14]), a7 = fmaxf(p[7], p[15]);
      a0 = fmaxf(a0, a4); a1 = fmaxf(a1, a5); a2 = fmaxf(a2, a6); a3 = fmaxf(a3, a7);
      a0 = fmaxf(a0, a2); a1 = fmaxf(a1, a3);
      float tm = fmaxf(a0, a1);
      if (!__all(tm <= m + 8.f)) {     // defer-max: rescale only on real growth (rare)
        float r = tm;
        r = fmaxf(r, __shfl_xor(r, 16));
        r = fmaxf(r, __shfl_xor(r, 32));
        float mn = fmaxf(m, r);
        float sc = fexp2(m - mn);
        m = mn;
        lsum *= sc;
#pragma unroll
        for (int dt = 0; dt < 8; ++dt)
#pragma unroll
          for (int jj = 0; jj < 4; ++jj) accO[dt][jj] *= sc;
      }
      float ps = 0.f;
#pragma unroll
      for (int i = 0; i < 16; ++i) {
        p[i] = fexp2(p[i] - m);
        ps += p[i];
      }
      lsum += ps;                      // per-lane partial, reduced at end

      f16x4 pf0 = { (f16)p[0],  (f16)p[1],  (f16)p[2],  (f16)p[3]  };
      f16x4 pf1 = { (f16)p[4],  (f16)p[5],  (f16)p[6],  (f16)p[7]  };
      f16x4 pf2 = { (f16)p[8],  (f16)p[9],  (f16)p[10], (f16)p[11] };
      f16x4 pf3 = { (f16)p[12], (f16)p[13], (f16)p[14], (f16)p[15] };
      const f16* vb0 = sVb + grp * 512 + voff0;
      const f16* vb1 = sVb + (grp + 4) * 512 + voff1;
      const f16* vb2 = sVb + (8 + grp) * 512 + voff0;
      const f16* vb3 = sVb + (12 + grp) * 512 + voff1;
#pragma unroll
      for (int dtp = 0; dtp < 8; ++dtp) {
        const int dt1 = dtp ^ 1;       // h=1 acc index; compile-time per unroll step
        f16x4 v0 = *reinterpret_cast<const f16x4*>(vb0 + dtp * 64);
        f16x4 v1 = *reinterpret_cast<const f16x4*>(vb1 + dtp * 64);
        f16x4 v2 = *reinterpret_cast<const f16x4*>(vb2 + dtp * 64);
        f16x4 v3 = *reinterpret_cast<const f16x4*>(vb3 + dtp * 64);
        accO[dtp] = __builtin_amdgcn_mfma_f32_16x16x16f16(v0, pf0, accO[dtp], 0, 0, 0);
        accO[dtp] = __builtin_amdgcn_mfma_f32_16x16x16f16(v1, pf1, accO[dtp], 0, 0, 0);
        accO[dt1] = __builtin_amdgcn_mfma_f32_16x16x16f16(v2, pf2, accO[dt1], 0, 0, 0);
        accO[dt1] = __builtin_amdgcn_mfma_f32_16x16x16f16(v3, pf3, accO[dt1], 0, 0, 0);
      }
    };

    stage(0, 0);
    asm volatile("s_waitcnt vmcnt(0)" ::: "memory");
    __builtin_amdgcn_s_barrier();

    // ---- main loop: branch-free, unmasked, always prefetch ----
    for (int t = 0; t < nt - 1; ++t) {
      const int buf = t & 1;
      stage(t + 1, buf ^ 1);           // t+1 <= nt-1 always valid here
      tile_step(&sK[buf][0], &sV[buf][0], t * 64, false);
      asm volatile("s_waitcnt vmcnt(0)" ::: "memory");  // next tile landed
      __builtin_amdgcn_s_barrier();
    }

    // ---- peeled last tile: causal mask (fully-masked rows exp to 0) ----
    {
      const int t = nt - 1, buf = t & 1;
      tile_step(&sK[buf][0], &sV[buf][0], t * 64, true);
    }

    lsum += __shfl_xor(lsum, 16);
    lsum += __shfl_xor(lsum, 32);
    float inv_l = 1.f / lsum;
    const size_t obase = ((size_t)(b * S_ + qt * 16 + qi)) * D_ + hq * DH_;
#pragma unroll
    for (int dt = 0; dt < 8; ++dt) {
      f16x4 st;
#pragma unroll
      for (int jj = 0; jj < 4; ++jj) st[jj] = (f16)(accO[dt][jj] * inv_l);
      *reinterpret_cast<f16x4*>(&O[obase + dt * 16 + grp * 4]) = st;
    }
    __builtin_amdgcn_s_barrier();   // all waves done before next task's stage(0,0)
  }
}

extern "C" void kernel_launch(void* const* d_in, const int* in_sizes, int n_in,
                              void* d_out, int out_size, void* d_ws, size_t ws_size,
                              hipStream_t stream) {
  const float* x  = (const float*)d_in[0];
  const float* Wq = (const float*)d_in[1];
  const float* bq = (const float*)d_in[2];
  const float* Wk = (const float*)d_in[3];
  const float* bk = (const float*)d_in[4];
  const float* Wv = (const float*)d_in[5];
  const float* bv = (const float*)d_in[6];
  const float* Wo = (const float*)d_in[7];
  const float* bo = (const float*)d_in[8];
  float* out = (float*)d_out;

  char* ws = (char*)d_ws;
  size_t off = 0;
  auto alloc = [&](size_t bytes) {
    char* p = ws + off;
    off += (bytes + 255) & ~(size_t)255;
    return p;
  };
  f16*   xh    = (f16*)alloc((size_t)B_ * S_ * D_ * 2);
  f16*   wqkv  = (f16*)alloc((size_t)NQKV_ * D_ * 2);
  f16*   woh   = (f16*)alloc((size_t)D_ * D_ * 2);
  f16*   qh    = (f16*)alloc((size_t)B_ * S_ * D_ * 2);
  f16*   kh    = (f16*)alloc((size_t)B_ * S_ * DKV_ * 2);
  f16*   v4h   = (f16*)alloc((size_t)B_ * S_ * DKV_ * 2);
  f16*   ah    = (f16*)alloc((size_t)B_ * S_ * D_ * 2);
  float* bqkv  = (float*)alloc((size_t)NQKV_ * 4);

  prep_kernel<<<dim3(2048), dim3(256), 0, stream>>>(
      x, Wq, Wk, Wv, Wo, bq, bk, bv, xh, wqkv, woh, bqkv);

  const int M = B_ * S_;
  gemm_core<1><<<dim3((M / 128) * (NQKV_ / 128)), 256, 0, stream>>>(
      xh, wqkv, bqkv, qh, kh, v4h, nullptr, M, NQKV_, D_, NQKV_ / 128);

  attn_kernel<<<dim3(512), 256, 0, stream>>>(qh, kh, v4h, ah);

  gemm_core<0><<<dim3((M / 128) * (D_ / 128)), 256, 0, stream>>>(
      ah, woh, bo, nullptr, nullptr, nullptr, out, M, D_, D_, D_ / 128);
}